// Round 5
// baseline (276.576 us; speedup 1.0000x reference)
//
#include <hip/hip_runtime.h>
#include <hip/hip_bf16.h>

#define S_LEN 4096
#define D_EMB 768
#define NH    12
#define HD    64
#define DQKV  2304
#define DFF   3072

typedef __attribute__((ext_vector_type(4))) short short4v;
typedef __attribute__((ext_vector_type(8))) short short8v;
typedef __attribute__((ext_vector_type(4))) float float4v;

static __device__ __forceinline__ float4v mfma16(short4v a, short4v b, float4v c) {
  return __builtin_amdgcn_mfma_f32_16x16x16bf16_1k(a, b, c, 0, 0, 0);
}

static __device__ __forceinline__ short bf16bits(float f) {
  __hip_bfloat16 h = __float2bfloat16(f);
  return *reinterpret_cast<short*>(&h);
}

// async global -> LDS, 16B per lane. LDS dest must be wave-uniform base + lane*16.
static __device__ __forceinline__ void gload16(const __hip_bfloat16* g, __hip_bfloat16* l) {
  __builtin_amdgcn_global_load_lds((const __attribute__((address_space(1))) void*)g,
                                   (__attribute__((address_space(3))) void*)l, 16, 0, 0);
}

// ---------------- LayerNorm: fp32 in -> bf16 out, one block per row ----------------
__global__ __launch_bounds__(256) void ln_kernel(const float* __restrict__ x,
    const float* __restrict__ g, const float* __restrict__ b,
    __hip_bfloat16* __restrict__ out)
{
  int row = blockIdx.x;
  int tid = threadIdx.x;
  const float* xr = x + (size_t)row * D_EMB;
  float v0 = xr[tid], v1 = xr[tid + 256], v2 = xr[tid + 512];
  float s  = v0 + v1 + v2;
  float sq = v0 * v0 + v1 * v1 + v2 * v2;
  #pragma unroll
  for (int off = 32; off >= 1; off >>= 1) {
    s  += __shfl_xor(s, off);
    sq += __shfl_xor(sq, off);
  }
  __shared__ float ss[4], ssq[4];
  if ((tid & 63) == 0) { ss[tid >> 6] = s; ssq[tid >> 6] = sq; }
  __syncthreads();
  s  = ss[0] + ss[1] + ss[2] + ss[3];
  sq = ssq[0] + ssq[1] + ssq[2] + ssq[3];
  float mean = s * (1.0f / D_EMB);
  float var  = sq * (1.0f / D_EMB) - mean * mean;
  float rstd = rsqrtf(var + 1e-5f);
  __hip_bfloat16* orow = out + (size_t)row * D_EMB;
  orow[tid]       = __float2bfloat16((v0 - mean) * rstd * g[tid]       + b[tid]);
  orow[tid + 256] = __float2bfloat16((v1 - mean) * rstd * g[tid + 256] + b[tid + 256]);
  orow[tid + 512] = __float2bfloat16((v2 - mean) * rstd * g[tid + 512] + b[tid + 512]);
}

// ---------------- fp32 [K][N] -> bf16 [N][K] tiled transpose ----------------
__global__ __launch_bounds__(256) void transpose_bf16_kernel(const float* __restrict__ in,
    __hip_bfloat16* __restrict__ out, int K, int N)
{
  __shared__ float t[32][33];
  int nb = N >> 5;
  int bn = blockIdx.x % nb, bk = blockIdx.x / nb;
  int tx = threadIdx.x & 31, ty = threadIdx.x >> 5;
  #pragma unroll
  for (int i = 0; i < 4; i++)
    t[ty + 8 * i][tx] = in[(size_t)(bk * 32 + ty + 8 * i) * N + bn * 32 + tx];
  __syncthreads();
  #pragma unroll
  for (int i = 0; i < 4; i++)
    out[(size_t)(bn * 32 + ty + 8 * i) * K + bk * 32 + tx] = __float2bfloat16(t[tx][ty + 8 * i]);
}

// ---------------- GEMM (m97 structure): C = A[M,K] * Bt[N,K]^T ----------------
// 128x128 tile, BK=64, global_load_lds w16, 16x16x32 MFMA, XOR chunk-swizzle, split-K.
// EPI 0: +bias -> bf16   EPI 1: +bias, GELU -> bf16   EPI 2: +bias +resid -> fp32
// EPI 3: raw fp32 partial to Cout + split*M*N (no bias)
template<int EPI>
__global__ __launch_bounds__(256) void gemm_kernel(
    const __hip_bfloat16* __restrict__ A,
    const __hip_bfloat16* __restrict__ Bt,
    const float* __restrict__ bias,
    const float* __restrict__ resid,
    void* __restrict__ Cout,
    int M, int N, int Kfull, int kChunk)
{
  __shared__ __hip_bfloat16 Asm[128 * 64];
  __shared__ __hip_bfloat16 Bsm[128 * 64];
  int nb = N >> 7, mb = M >> 7;
  int tilesPer = nb * mb;
  int split = blockIdx.x / tilesPer;
  int b2 = blockIdx.x % tilesPer;
  int bx = b2 % nb, by = b2 / nb;
  int m0 = by << 7, n0 = bx << 7;
  int k0 = split * kChunk;
  int tid = threadIdx.x;
  int lane = tid & 63, lg = lane >> 4, li = lane & 15;
  int w = tid >> 6, wr = w >> 1, wc = w & 1;

  int sr  = tid >> 3;
  int scn = (tid & 7) ^ (sr & 7);
  const __hip_bfloat16* aSrc = A  + (size_t)(m0 + sr) * Kfull + k0 + scn * 8;
  const __hip_bfloat16* bSrc = Bt + (size_t)(n0 + sr) * Kfull + k0 + scn * 8;
  __hip_bfloat16* aDst = Asm + tid * 8;
  __hip_bfloat16* bDst = Bsm + tid * 8;
  const size_t rowStep = (size_t)32 * Kfull;

  float4v acc[4][4];
  #pragma unroll
  for (int i = 0; i < 4; i++)
    #pragma unroll
    for (int j = 0; j < 4; j++) {
      float4v z = {0.f, 0.f, 0.f, 0.f};
      acc[i][j] = z;
    }

  int sw = li & 7;

  for (int kt = 0; kt < kChunk; kt += 64) {
    #pragma unroll
    for (int i = 0; i < 4; i++) {
      gload16(aSrc + i * rowStep, aDst + i * 2048);
      gload16(bSrc + i * rowStep, bDst + i * 2048);
    }
    aSrc += 64; bSrc += 64;
    __syncthreads();
    #pragma unroll
    for (int kk = 0; kk < 2; kk++) {
      short8v af[4], bf[4];
      #pragma unroll
      for (int f = 0; f < 4; f++) {
        int ar = wr * 64 + f * 16 + li;
        int br = wc * 64 + f * 16 + li;
        int ch = ((kk << 2) | lg) ^ sw;
        af[f] = *(const short8v*)(Asm + ar * 64 + ch * 8);
        bf[f] = *(const short8v*)(Bsm + br * 64 + ch * 8);
      }
      #pragma unroll
      for (int fr = 0; fr < 4; fr++)
        #pragma unroll
        for (int fc = 0; fc < 4; fc++)
          acc[fr][fc] = __builtin_amdgcn_mfma_f32_16x16x32_bf16(af[fr], bf[fc], acc[fr][fc], 0, 0, 0);
    }
    __syncthreads();
  }

  #pragma unroll
  for (int fr = 0; fr < 4; fr++) {
    int row = m0 + wr * 64 + fr * 16 + lg * 4;
    #pragma unroll
    for (int fc = 0; fc < 4; fc++) {
      int col = n0 + wc * 64 + fc * 16 + li;
      float bv = (EPI == 3) ? 0.f : bias[col];
      #pragma unroll
      for (int r = 0; r < 4; r++) {
        float v = acc[fr][fc][r] + bv;
        size_t idx = (size_t)(row + r) * N + col;
        if (EPI == 1) {
          v = 0.5f * v * (1.0f + erff(v * 0.70710678118654752f));
          ((__hip_bfloat16*)Cout)[idx] = __float2bfloat16(v);
        } else if (EPI == 2) {
          ((float*)Cout)[idx] = v + resid[idx];
        } else if (EPI == 3) {
          ((float*)Cout)[(size_t)split * M * N + idx] = v;
        } else {
          ((__hip_bfloat16*)Cout)[idx] = __float2bfloat16(v);
        }
      }
    }
  }
}

// ---------------- split-K reduce: out = resid + bias + sum(parts) ----------------
template<int NS>
__global__ __launch_bounds__(256) void reduce_kernel(const float* __restrict__ parts,
    const float* __restrict__ bias, const float* __restrict__ resid,
    float* __restrict__ out, int n4)
{
  int stride = gridDim.x * 256;
  for (int e = blockIdx.x * 256 + threadIdx.x; e < n4; e += stride) {
    float4v acc = *(const float4v*)(resid + 4 * (size_t)e);
    int col = (e * 4) % D_EMB;
    float4v bv = *(const float4v*)(bias + col);
    acc += bv;
    #pragma unroll
    for (int s = 0; s < NS; s++)
      acc += *(const float4v*)(parts + (size_t)s * 4 * n4 + 4 * (size_t)e);
    *(float4v*)(out + 4 * (size_t)e) = acc;
  }
}

// ---------------- causal flash attention v5 ----------------
// Swapped-operand (S^T=K*Q^T), in-register P, K double-buffered via swizzled
// global_load_lds (prefetch stays in flight across raw s_barrier), single V buf,
// balanced XCD remap, exp2-domain softmax with defer-max.
__global__ __launch_bounds__(256) void attn_kernel(const __hip_bfloat16* __restrict__ kqv,
                                                   __hip_bfloat16* __restrict__ y)
{
  __shared__ __hip_bfloat16 Ksm[2][64 * 64];   // [kv][d] linear, swizzled content
  __shared__ __hip_bfloat16 Vtsm[64][66];      // [d][kv]

  // balanced XCD remap: XCD x gets 48 pairs {qb, 63-qb} covering <=2 heads
  int bid = blockIdx.x;
  int xcd = bid & 7, r = bid >> 3;
  int pi = 48 * xcd + (r >> 1);
  int h  = pi >> 5;
  int qi = pi & 31;
  int qb = (r & 1) ? qi : 63 - qi;   // alternate heavy/light

  int tid = threadIdx.x;
  int w = tid >> 6, lane = tid & 63, lg = lane >> 4, li = lane & 15;

  // Q as B-operand of 16x16x32: lane li = q-col, k(d) = kk*32 + 8*lg + j
  short8v q8[2];
  {
    const __hip_bfloat16* qp = kqv + (size_t)(qb * 64 + w * 16 + li) * DQKV + D_EMB + h * HD + 8 * lg;
    q8[0] = *(const short8v*)(qp);
    q8[1] = *(const short8v*)(qp + 32);
  }

  float m = -1e30f, lsum = 0.f;
  float4v o[4];
  #pragma unroll
  for (int fc = 0; fc < 4; fc++) { float4v z = {0.f,0.f,0.f,0.f}; o[fc] = z; }

  // K staging roles (global_load_lds, 2 issues x 256 thr x 16B)
  int ksr  = tid >> 3;
  int kscn = (tid & 7) ^ (ksr & 7);
  const __hip_bfloat16* kSrc0 = kqv + h * HD + (size_t)ksr * DQKV + kscn * 8;
  // V staging roles (register path, transposed write)
  int vr = (tid >> 3) << 1, vc = (tid & 7) << 3;
  const __hip_bfloat16* vSrc0 = kqv + 2 * D_EMB + h * HD + (size_t)vr * DQKV + vc;

  const size_t kRowStep = (size_t)32 * DQKV;
  const size_t tileStep = (size_t)64 * DQKV;

  short8v vA, vB;
  // prologue: K tile 0 -> buf 0, V tile 0 -> regs
  gload16(kSrc0,            &Ksm[0][tid * 8]);
  gload16(kSrc0 + kRowStep, &Ksm[0][tid * 8 + 2048]);
  vA = *(const short8v*)(vSrc0);
  vB = *(const short8v*)(vSrc0 + DQKV);

  const float scl = 0.18033688011f;  // 0.125 * log2(e)
  int sw = li & 7;

  for (int kb = 0; kb <= qb; kb++) {
    int p = kb & 1;
    __syncthreads();   // (a) full drain: K[p] landed, prev tile's LDS reads done, V regs landed

    // V transposed write for tile kb
    #pragma unroll
    for (int j = 0; j < 8; j++) {
      unsigned int pk = (unsigned int)(unsigned short)vA[j]
                      | ((unsigned int)(unsigned short)vB[j] << 16);
      *reinterpret_cast<unsigned int*>(&Vtsm[vc + j][vr]) = pk;
    }
    // issue K prefetch for kb+1 into the other buffer; stays in flight across (b)
    if (kb < qb) {
      const __hip_bfloat16* ks = kSrc0 + (size_t)(kb + 1) * tileStep;
      gload16(ks,            &Ksm[p ^ 1][tid * 8]);
      gload16(ks + kRowStep, &Ksm[p ^ 1][tid * 8 + 2048]);
    }
    asm volatile("s_waitcnt lgkmcnt(0)" ::: "memory");
    __builtin_amdgcn_s_barrier();  // (b) light barrier: vmcnt NOT drained

    // V register prefetch for kb+1 (latency hides under compute)
    if (kb < qb) {
      const __hip_bfloat16* vs = vSrc0 + (size_t)(kb + 1) * tileStep;
      vA = *(const short8v*)(vs);
      vB = *(const short8v*)(vs + DQKV);
    }

    // S^T = K * Q^T : s[fc] covers kv = fc*16 + 4*lg + r, q = li
    float4v s[4];
    #pragma unroll
    for (int fc = 0; fc < 4; fc++) { float4v z = {0.f,0.f,0.f,0.f}; s[fc] = z; }
    #pragma unroll
    for (int kk = 0; kk < 2; kk++) {
      #pragma unroll
      for (int fc = 0; fc < 4; fc++) {
        int ch = ((kk << 2) | lg) ^ sw;
        short8v kf = *(const short8v*)(&Ksm[p][(fc * 16 + li) * 64 + ch * 8]);
        s[fc] = __builtin_amdgcn_mfma_f32_16x16x32_bf16(kf, q8[kk], s[fc], 0, 0, 0);
      }
    }

    // online softmax in exp2 domain, defer-max (THR=8 -> P bounded by 256)
    bool diag = (kb == qb);
    float pmax = -1e30f;
    #pragma unroll
    for (int fc = 0; fc < 4; fc++) {
      #pragma unroll
      for (int rr = 0; rr < 4; rr++) {
        float v = s[fc][rr] * scl;
        if (diag && (fc * 16 + 4 * lg + rr) > (w * 16 + li)) v = -1e30f;
        s[fc][rr] = v;
        pmax = fmaxf(pmax, v);
      }
    }
    pmax = fmaxf(pmax, __shfl_xor(pmax, 16));
    pmax = fmaxf(pmax, __shfl_xor(pmax, 32));
    if (!__all(pmax - m <= 8.0f)) {
      float mn = fmaxf(m, pmax);
      float alpha = exp2f(m - mn);
      lsum *= alpha;
      #pragma unroll
      for (int fc = 0; fc < 4; fc++) {
        #pragma unroll
        for (int rr = 0; rr < 4; rr++) o[fc][rr] *= alpha;
      }
      m = mn;
    }
    float rs = 0.f;
    #pragma unroll
    for (int fc = 0; fc < 4; fc++) {
      #pragma unroll
      for (int rr = 0; rr < 4; rr++) {
        float pv = exp2f(s[fc][rr] - m);
        s[fc][rr] = pv;
        rs += pv;
      }
    }
    rs += __shfl_xor(rs, 16);
    rs += __shfl_xor(rs, 32);
    lsum += rs;

    // P^T fragments (B-operand of 16x16x16) straight from registers
    short4v pb[4];
    #pragma unroll
    for (int kk = 0; kk < 4; kk++) {
      short4v t;
      #pragma unroll
      for (int rr = 0; rr < 4; rr++) t[rr] = bf16bits(s[kk][rr]);
      pb[kk] = t;
    }

    // O^T += V^T * P^T
    #pragma unroll
    for (int kk = 0; kk < 4; kk++) {
      #pragma unroll
      for (int fc = 0; fc < 4; fc++) {
        short4v vf = *(const short4v*)(&Vtsm[fc * 16 + li][kk * 16 + 4 * lg]);
        o[fc] = mfma16(vf, pb[kk], o[fc]);
      }
    }
  }

  float inv = 1.0f / lsum;
  int qrow = qb * 64 + w * 16 + li;
  #pragma unroll
  for (int fc = 0; fc < 4; fc++) {
    short4v ov;
    #pragma unroll
    for (int rr = 0; rr < 4; rr++) ov[rr] = bf16bits(o[fc][rr] * inv);
    *reinterpret_cast<short4v*>(y + (size_t)qrow * D_EMB + h * HD + fc * 16 + 4 * lg) = ov;
  }
}

// ---------------- launch ----------------
extern "C" void kernel_launch(void* const* d_in, const int* in_sizes, int n_in,
                              void* d_out, int out_size, void* d_ws, size_t ws_size,
                              hipStream_t stream)
{
  const float* x      = (const float*)d_in[0];
  const float* w_qkv  = (const float*)d_in[1];
  const float* b_qkv  = (const float*)d_in[2];
  const float* w_proj = (const float*)d_in[3];
  const float* b_proj = (const float*)d_in[4];
  const float* w_fc1  = (const float*)d_in[5];
  const float* b_fc1  = (const float*)d_in[6];
  const float* w_fc2  = (const float*)d_in[7];
  const float* b_fc2  = (const float*)d_in[8];
  const float* ln1_g  = (const float*)d_in[9];
  const float* ln1_b  = (const float*)d_in[10];
  const float* ln2_g  = (const float*)d_in[11];
  const float* ln2_b  = (const float*)d_in[12];

  char* ws = (char*)d_ws;
  size_t off = 0;
  __hip_bfloat16* wqkvT = (__hip_bfloat16*)(ws + off); off += (size_t)DQKV * D_EMB * 2;
  __hip_bfloat16* wprojT= (__hip_bfloat16*)(ws + off); off += (size_t)D_EMB * D_EMB * 2;
  __hip_bfloat16* wfc1T = (__hip_bfloat16*)(ws + off); off += (size_t)DFF * D_EMB * 2;
  __hip_bfloat16* wfc2T = (__hip_bfloat16*)(ws + off); off += (size_t)D_EMB * DFF * 2;
  __hip_bfloat16* lnbuf = (__hip_bfloat16*)(ws + off); off += (size_t)S_LEN * D_EMB * 2;
  __hip_bfloat16* kqv   = (__hip_bfloat16*)(ws + off);
  __hip_bfloat16* hbuf  = kqv;                         off += (size_t)S_LEN * DQKV * 2;
  __hip_bfloat16* ybuf  = (__hip_bfloat16*)(ws + off); off += (size_t)S_LEN * D_EMB * 2;
  float*          x1    = (float*)(ws + off);          off += (size_t)S_LEN * D_EMB * 4;
  float*          part  = (float*)(ws + off);
  size_t needSplit = off + (size_t)4 * S_LEN * D_EMB * 4;   // 4 fp32 partial planes
  bool splitk = (ws_size >= needSplit);
  const int MN4 = S_LEN * D_EMB / 4;
  (void)in_sizes; (void)n_in; (void)out_size;

  transpose_bf16_kernel<<<dim3((DQKV/32)*(D_EMB/32)), dim3(256), 0, stream>>>(w_qkv,  wqkvT, D_EMB, DQKV);
  transpose_bf16_kernel<<<dim3((D_EMB/32)*(D_EMB/32)), dim3(256), 0, stream>>>(w_proj, wprojT, D_EMB, D_EMB);
  transpose_bf16_kernel<<<dim3((DFF/32)*(D_EMB/32)),   dim3(256), 0, stream>>>(w_fc1,  wfc1T, D_EMB, DFF);
  transpose_bf16_kernel<<<dim3((D_EMB/32)*(DFF/32)),   dim3(256), 0, stream>>>(w_fc2,  wfc2T, DFF, D_EMB);

  ln_kernel<<<dim3(S_LEN), dim3(256), 0, stream>>>(x, ln1_g, ln1_b, lnbuf);
  gemm_kernel<0><<<dim3((DQKV/128)*(S_LEN/128)), dim3(256), 0, stream>>>(
      lnbuf, wqkvT, b_qkv, nullptr, kqv, S_LEN, DQKV, D_EMB, D_EMB);
  attn_kernel<<<dim3(NH * (S_LEN/64)), dim3(256), 0, stream>>>(kqv, ybuf);

  if (splitk) {
    // proj: split-K x3 (576 blocks), then reduce + bias + residual(x) -> x1
    gemm_kernel<3><<<dim3((D_EMB/128)*(S_LEN/128)*3), dim3(256), 0, stream>>>(
        ybuf, wprojT, nullptr, nullptr, part, S_LEN, D_EMB, D_EMB, D_EMB/3);
    reduce_kernel<3><<<dim3(1024), dim3(256), 0, stream>>>(part, b_proj, x, x1, MN4);
  } else {
    gemm_kernel<2><<<dim3((D_EMB/128)*(S_LEN/128)), dim3(256), 0, stream>>>(
        ybuf, wprojT, b_proj, x, x1, S_LEN, D_EMB, D_EMB, D_EMB);
  }

  ln_kernel<<<dim3(S_LEN), dim3(256), 0, stream>>>(x1, ln2_g, ln2_b, lnbuf);
  gemm_kernel<1><<<dim3((DFF/128)*(S_LEN/128)), dim3(256), 0, stream>>>(
      lnbuf, wfc1T, b_fc1, nullptr, hbuf, S_LEN, DFF, D_EMB, D_EMB);

  if (splitk) {
    // fc2: split-K x4 (768 blocks), then reduce + bias + residual(x1) -> out
    gemm_kernel<3><<<dim3((D_EMB/128)*(S_LEN/128)*4), dim3(256), 0, stream>>>(
        hbuf, wfc2T, nullptr, nullptr, part, S_LEN, D_EMB, DFF, DFF/4);
    reduce_kernel<4><<<dim3(1024), dim3(256), 0, stream>>>(part, b_fc2, x1, (float*)d_out, MN4);
  } else {
    gemm_kernel<2><<<dim3((D_EMB/128)*(S_LEN/128)), dim3(256), 0, stream>>>(
        hbuf, wfc2T, b_fc2, x1, (float*)d_out, S_LEN, D_EMB, DFF, DFF);
  }
}

// Round 6
// 265.080 us; speedup vs baseline: 1.0434x; 1.0434x over previous
//
#include <hip/hip_runtime.h>
#include <hip/hip_bf16.h>

#define S_LEN 4096
#define D_EMB 768
#define NH    12
#define HD    64
#define DQKV  2304
#define DFF   3072
#define NTASKS (NH * (S_LEN / 64))   // 768
#define ATTN_BLOCKS 1024

typedef __attribute__((ext_vector_type(4))) short short4v;
typedef __attribute__((ext_vector_type(8))) short short8v;
typedef __attribute__((ext_vector_type(4))) float float4v;

static __device__ __forceinline__ float4v mfma16(short4v a, short4v b, float4v c) {
  return __builtin_amdgcn_mfma_f32_16x16x16bf16_1k(a, b, c, 0, 0, 0);
}

static __device__ __forceinline__ short bf16bits(float f) {
  __hip_bfloat16 h = __float2bfloat16(f);
  return *reinterpret_cast<short*>(&h);
}

// async global -> LDS, 16B per lane. LDS dest must be wave-uniform base + lane*16.
static __device__ __forceinline__ void gload16(const __hip_bfloat16* g, __hip_bfloat16* l) {
  __builtin_amdgcn_global_load_lds((const __attribute__((address_space(1))) void*)g,
                                   (__attribute__((address_space(3))) void*)l, 16, 0, 0);
}

// ---------------- LayerNorm: fp32 in -> bf16 out, one block per row ----------------
__global__ __launch_bounds__(256) void ln_kernel(const float* __restrict__ x,
    const float* __restrict__ g, const float* __restrict__ b,
    __hip_bfloat16* __restrict__ out)
{
  int row = blockIdx.x;
  int tid = threadIdx.x;
  const float* xr = x + (size_t)row * D_EMB;
  float v0 = xr[tid], v1 = xr[tid + 256], v2 = xr[tid + 512];
  float s  = v0 + v1 + v2;
  float sq = v0 * v0 + v1 * v1 + v2 * v2;
  #pragma unroll
  for (int off = 32; off >= 1; off >>= 1) {
    s  += __shfl_xor(s, off);
    sq += __shfl_xor(sq, off);
  }
  __shared__ float ss[4], ssq[4];
  if ((tid & 63) == 0) { ss[tid >> 6] = s; ssq[tid >> 6] = sq; }
  __syncthreads();
  s  = ss[0] + ss[1] + ss[2] + ss[3];
  sq = ssq[0] + ssq[1] + ssq[2] + ssq[3];
  float mean = s * (1.0f / D_EMB);
  float var  = sq * (1.0f / D_EMB) - mean * mean;
  float rstd = rsqrtf(var + 1e-5f);
  __hip_bfloat16* orow = out + (size_t)row * D_EMB;
  orow[tid]       = __float2bfloat16((v0 - mean) * rstd * g[tid]       + b[tid]);
  orow[tid + 256] = __float2bfloat16((v1 - mean) * rstd * g[tid + 256] + b[tid + 256]);
  orow[tid + 512] = __float2bfloat16((v2 - mean) * rstd * g[tid + 512] + b[tid + 512]);
}

// ---------------- fp32 [K][N] -> bf16 [N][K] tiled transpose ----------------
__global__ __launch_bounds__(256) void transpose_bf16_kernel(const float* __restrict__ in,
    __hip_bfloat16* __restrict__ out, int K, int N)
{
  __shared__ float t[32][33];
  int nb = N >> 5;
  int bn = blockIdx.x % nb, bk = blockIdx.x / nb;
  int tx = threadIdx.x & 31, ty = threadIdx.x >> 5;
  #pragma unroll
  for (int i = 0; i < 4; i++)
    t[ty + 8 * i][tx] = in[(size_t)(bk * 32 + ty + 8 * i) * N + bn * 32 + tx];
  __syncthreads();
  #pragma unroll
  for (int i = 0; i < 4; i++)
    out[(size_t)(bn * 32 + ty + 8 * i) * K + bk * 32 + tx] = __float2bfloat16(t[tx][ty + 8 * i]);
}

// ---------------- GEMM (m97 structure): C = A[M,K] * Bt[N,K]^T ----------------
// EPI 0: +bias -> bf16   EPI 1: +bias, GELU -> bf16   EPI 2: +bias +resid -> fp32
// EPI 3: raw fp32 partial to Cout + split*M*N (no bias)
template<int EPI>
__global__ __launch_bounds__(256) void gemm_kernel(
    const __hip_bfloat16* __restrict__ A,
    const __hip_bfloat16* __restrict__ Bt,
    const float* __restrict__ bias,
    const float* __restrict__ resid,
    void* __restrict__ Cout,
    int M, int N, int Kfull, int kChunk)
{
  __shared__ __hip_bfloat16 Asm[128 * 64];
  __shared__ __hip_bfloat16 Bsm[128 * 64];
  int nb = N >> 7, mb = M >> 7;
  int tilesPer = nb * mb;
  int split = blockIdx.x / tilesPer;
  int b2 = blockIdx.x % tilesPer;
  int bx = b2 % nb, by = b2 / nb;
  int m0 = by << 7, n0 = bx << 7;
  int k0 = split * kChunk;
  int tid = threadIdx.x;
  int lane = tid & 63, lg = lane >> 4, li = lane & 15;
  int w = tid >> 6, wr = w >> 1, wc = w & 1;

  int sr  = tid >> 3;
  int scn = (tid & 7) ^ (sr & 7);
  const __hip_bfloat16* aSrc = A  + (size_t)(m0 + sr) * Kfull + k0 + scn * 8;
  const __hip_bfloat16* bSrc = Bt + (size_t)(n0 + sr) * Kfull + k0 + scn * 8;
  __hip_bfloat16* aDst = Asm + tid * 8;
  __hip_bfloat16* bDst = Bsm + tid * 8;
  const size_t rowStep = (size_t)32 * Kfull;

  float4v acc[4][4];
  #pragma unroll
  for (int i = 0; i < 4; i++)
    #pragma unroll
    for (int j = 0; j < 4; j++) {
      float4v z = {0.f, 0.f, 0.f, 0.f};
      acc[i][j] = z;
    }

  int sw = li & 7;

  for (int kt = 0; kt < kChunk; kt += 64) {
    #pragma unroll
    for (int i = 0; i < 4; i++) {
      gload16(aSrc + i * rowStep, aDst + i * 2048);
      gload16(bSrc + i * rowStep, bDst + i * 2048);
    }
    aSrc += 64; bSrc += 64;
    __syncthreads();
    #pragma unroll
    for (int kk = 0; kk < 2; kk++) {
      short8v af[4], bf[4];
      #pragma unroll
      for (int f = 0; f < 4; f++) {
        int ar = wr * 64 + f * 16 + li;
        int br = wc * 64 + f * 16 + li;
        int ch = ((kk << 2) | lg) ^ sw;
        af[f] = *(const short8v*)(Asm + ar * 64 + ch * 8);
        bf[f] = *(const short8v*)(Bsm + br * 64 + ch * 8);
      }
      #pragma unroll
      for (int fr = 0; fr < 4; fr++)
        #pragma unroll
        for (int fc = 0; fc < 4; fc++)
          acc[fr][fc] = __builtin_amdgcn_mfma_f32_16x16x32_bf16(af[fr], bf[fc], acc[fr][fc], 0, 0, 0);
    }
    __syncthreads();
  }

  #pragma unroll
  for (int fr = 0; fr < 4; fr++) {
    int row = m0 + wr * 64 + fr * 16 + lg * 4;
    #pragma unroll
    for (int fc = 0; fc < 4; fc++) {
      int col = n0 + wc * 64 + fc * 16 + li;
      float bv = (EPI == 3) ? 0.f : bias[col];
      #pragma unroll
      for (int r = 0; r < 4; r++) {
        float v = acc[fr][fc][r] + bv;
        size_t idx = (size_t)(row + r) * N + col;
        if (EPI == 1) {
          v = 0.5f * v * (1.0f + erff(v * 0.70710678118654752f));
          ((__hip_bfloat16*)Cout)[idx] = __float2bfloat16(v);
        } else if (EPI == 2) {
          ((float*)Cout)[idx] = v + resid[idx];
        } else if (EPI == 3) {
          ((float*)Cout)[(size_t)split * M * N + idx] = v;
        } else {
          ((__hip_bfloat16*)Cout)[idx] = __float2bfloat16(v);
        }
      }
    }
  }
}

// ---------------- split-K reduce: out = resid + bias + sum(parts) ----------------
template<int NS>
__global__ __launch_bounds__(256) void reduce_kernel(const float* __restrict__ parts,
    const float* __restrict__ bias, const float* __restrict__ resid,
    float* __restrict__ out, int n4)
{
  int stride = gridDim.x * 256;
  for (int e = blockIdx.x * 256 + threadIdx.x; e < n4; e += stride) {
    float4v acc = *(const float4v*)(resid + 4 * (size_t)e);
    int col = (e * 4) % D_EMB;
    float4v bv = *(const float4v*)(bias + col);
    acc += bv;
    #pragma unroll
    for (int s = 0; s < NS; s++)
      acc += *(const float4v*)(parts + (size_t)s * 4 * n4 + 4 * (size_t)e);
    *(float4v*)(out + 4 * (size_t)e) = acc;
  }
}

__global__ void zero_counter_kernel(int* c) { *c = 0; }

// ---------------- causal flash attention v6: persistent work-queue ----------------
// Swapped-operand (S^T=K*Q^T), in-register P, single-buffer K (swizzled gload) and
// V (stride-68 padded), 2 barriers/tile, exp2 softmax + defer-max, atomic task pop.
__global__ __launch_bounds__(256) void attn_kernel(const __hip_bfloat16* __restrict__ kqv,
                                                   __hip_bfloat16* __restrict__ y,
                                                   int* __restrict__ counter)
{
  __shared__ __hip_bfloat16 Ksm[64 * 64];   // [kv][d] linear, swizzled content
  __shared__ __hip_bfloat16 Vtsm[64][68];   // [d][kv], pad->conflict-free b64 reads
  __shared__ int task_s;

  int tid = threadIdx.x;
  int w = tid >> 6, lane = tid & 63, lg = lane >> 4, li = lane & 15;
  int sw = li & 7;

  // staging roles (constant across tasks)
  int ksr  = tid >> 3;                    // K row 0..31 (+32 second issue)
  int kscn = (tid & 7) ^ (ksr & 7);       // swizzled source chunk
  int vr = (tid >> 3) << 1, vc = (tid & 7) << 3;
  const size_t kRowStep = (size_t)32 * DQKV;
  const float scl = 0.18033688011f;       // 0.125 * log2(e)

  for (;;) {
    __syncthreads();                       // protect task_s + LDS across tasks
    if (tid == 0) task_s = atomicAdd(counter, 1);
    __syncthreads();
    int task = task_s;
    if (task >= NTASKS) return;
    int h  = task % NH;
    int qb = 63 - (task / NH);             // heavy tasks first

    const __hip_bfloat16* kSrc0 = kqv + h * HD + (size_t)ksr * DQKV + kscn * 8;
    const __hip_bfloat16* vSrc0 = kqv + 2 * D_EMB + h * HD + (size_t)vr * DQKV + vc;

    // Q as B-operand of 16x16x32: lane li = q-col, k(d) = kk*32 + 8*lg + j
    short8v q8[2];
    {
      const __hip_bfloat16* qp = kqv + (size_t)(qb * 64 + w * 16 + li) * DQKV + D_EMB + h * HD + 8 * lg;
      q8[0] = *(const short8v*)(qp);
      q8[1] = *(const short8v*)(qp + 32);
    }

    float m = -1e30f, lsum = 0.f;
    float4v o[4];
    #pragma unroll
    for (int fc = 0; fc < 4; fc++) { float4v z = {0.f,0.f,0.f,0.f}; o[fc] = z; }

    short8v vA, vB;
    vA = *(const short8v*)(vSrc0);
    vB = *(const short8v*)(vSrc0 + DQKV);

    for (int kb = 0; kb <= qb; kb++) {
      __syncthreads();                     // (a) prev-tile LDS reads done; V regs landed
      {
        const __hip_bfloat16* ks = kSrc0 + (size_t)kb * 64 * DQKV;
        gload16(ks,            Ksm + tid * 8);
        gload16(ks + kRowStep, Ksm + tid * 8 + 2048);
      }
      #pragma unroll
      for (int j = 0; j < 8; j++) {
        unsigned int pk = (unsigned int)(unsigned short)vA[j]
                        | ((unsigned int)(unsigned short)vB[j] << 16);
        *reinterpret_cast<unsigned int*>(&Vtsm[vc + j][vr]) = pk;
      }
      __syncthreads();                     // (b) drains vmcnt: K staged, V written

      if (kb < qb) {                       // V reg prefetch; lands by next (a)
        const __hip_bfloat16* vs = vSrc0 + (size_t)(kb + 1) * 64 * DQKV;
        vA = *(const short8v*)(vs);
        vB = *(const short8v*)(vs + DQKV);
      }

      // S^T = K * Q^T : s[fc] covers kv = fc*16 + 4*lg + r, q = li
      float4v s[4];
      #pragma unroll
      for (int fc = 0; fc < 4; fc++) { float4v z = {0.f,0.f,0.f,0.f}; s[fc] = z; }
      #pragma unroll
      for (int kk = 0; kk < 2; kk++) {
        #pragma unroll
        for (int fc = 0; fc < 4; fc++) {
          int ch = ((kk << 2) | lg) ^ sw;
          short8v kf = *(const short8v*)(Ksm + (fc * 16 + li) * 64 + ch * 8);
          s[fc] = __builtin_amdgcn_mfma_f32_16x16x32_bf16(kf, q8[kk], s[fc], 0, 0, 0);
        }
      }

      // online softmax (exp2 domain, defer-max THR=8)
      bool diag = (kb == qb);
      float pmax = -1e30f;
      #pragma unroll
      for (int fc = 0; fc < 4; fc++) {
        #pragma unroll
        for (int rr = 0; rr < 4; rr++) {
          float v = s[fc][rr] * scl;
          if (diag && (fc * 16 + 4 * lg + rr) > (w * 16 + li)) v = -1e30f;
          s[fc][rr] = v;
          pmax = fmaxf(pmax, v);
        }
      }
      pmax = fmaxf(pmax, __shfl_xor(pmax, 16));
      pmax = fmaxf(pmax, __shfl_xor(pmax, 32));
      if (!__all(pmax - m <= 8.0f)) {
        float mn = fmaxf(m, pmax);
        float alpha = exp2f(m - mn);
        lsum *= alpha;
        #pragma unroll
        for (int fc = 0; fc < 4; fc++) {
          #pragma unroll
          for (int rr = 0; rr < 4; rr++) o[fc][rr] *= alpha;
        }
        m = mn;
      }
      float rs = 0.f;
      #pragma unroll
      for (int fc = 0; fc < 4; fc++) {
        #pragma unroll
        for (int rr = 0; rr < 4; rr++) {
          float pv = exp2f(s[fc][rr] - m);
          s[fc][rr] = pv;
          rs += pv;
        }
      }
      rs += __shfl_xor(rs, 16);
      rs += __shfl_xor(rs, 32);
      lsum += rs;

      // P^T fragments (B-operand of 16x16x16) straight from registers
      short4v pb[4];
      #pragma unroll
      for (int kk = 0; kk < 4; kk++) {
        short4v t;
        #pragma unroll
        for (int rr = 0; rr < 4; rr++) t[rr] = bf16bits(s[kk][rr]);
        pb[kk] = t;
      }

      // O^T += V^T * P^T
      #pragma unroll
      for (int kk = 0; kk < 4; kk++) {
        #pragma unroll
        for (int fc = 0; fc < 4; fc++) {
          short4v vf = *(const short4v*)(&Vtsm[fc * 16 + li][kk * 16 + 4 * lg]);
          o[fc] = mfma16(vf, pb[kk], o[fc]);
        }
      }
    }

    float inv = 1.0f / lsum;
    int qrow = qb * 64 + w * 16 + li;
    #pragma unroll
    for (int fc = 0; fc < 4; fc++) {
      short4v ov;
      #pragma unroll
      for (int rr = 0; rr < 4; rr++) ov[rr] = bf16bits(o[fc][rr] * inv);
      *reinterpret_cast<short4v*>(y + (size_t)qrow * D_EMB + h * HD + fc * 16 + 4 * lg) = ov;
    }
  }
}

// ---------------- launch ----------------
extern "C" void kernel_launch(void* const* d_in, const int* in_sizes, int n_in,
                              void* d_out, int out_size, void* d_ws, size_t ws_size,
                              hipStream_t stream)
{
  const float* x      = (const float*)d_in[0];
  const float* w_qkv  = (const float*)d_in[1];
  const float* b_qkv  = (const float*)d_in[2];
  const float* w_proj = (const float*)d_in[3];
  const float* b_proj = (const float*)d_in[4];
  const float* w_fc1  = (const float*)d_in[5];
  const float* b_fc1  = (const float*)d_in[6];
  const float* w_fc2  = (const float*)d_in[7];
  const float* b_fc2  = (const float*)d_in[8];
  const float* ln1_g  = (const float*)d_in[9];
  const float* ln1_b  = (const float*)d_in[10];
  const float* ln2_g  = (const float*)d_in[11];
  const float* ln2_b  = (const float*)d_in[12];

  char* ws = (char*)d_ws;
  size_t off = 0;
  __hip_bfloat16* wqkvT = (__hip_bfloat16*)(ws + off); off += (size_t)DQKV * D_EMB * 2;
  __hip_bfloat16* wprojT= (__hip_bfloat16*)(ws + off); off += (size_t)D_EMB * D_EMB * 2;
  __hip_bfloat16* wfc1T = (__hip_bfloat16*)(ws + off); off += (size_t)DFF * D_EMB * 2;
  __hip_bfloat16* wfc2T = (__hip_bfloat16*)(ws + off); off += (size_t)D_EMB * DFF * 2;
  __hip_bfloat16* lnbuf = (__hip_bfloat16*)(ws + off); off += (size_t)S_LEN * D_EMB * 2;
  __hip_bfloat16* kqv   = (__hip_bfloat16*)(ws + off);
  __hip_bfloat16* hbuf  = kqv;                         off += (size_t)S_LEN * DQKV * 2;
  __hip_bfloat16* ybuf  = (__hip_bfloat16*)(ws + off); off += (size_t)S_LEN * D_EMB * 2;
  float*          x1    = (float*)(ws + off);          off += (size_t)S_LEN * D_EMB * 4;
  int*            cnt   = (int*)(ws + off);            off += 256;
  float*          part  = (float*)(ws + off);
  size_t needSplit = off + (size_t)4 * S_LEN * D_EMB * 4;
  bool splitk = (ws_size >= needSplit);
  const int MN4 = S_LEN * D_EMB / 4;
  (void)in_sizes; (void)n_in; (void)out_size;

  transpose_bf16_kernel<<<dim3((DQKV/32)*(D_EMB/32)), dim3(256), 0, stream>>>(w_qkv,  wqkvT, D_EMB, DQKV);
  transpose_bf16_kernel<<<dim3((D_EMB/32)*(D_EMB/32)), dim3(256), 0, stream>>>(w_proj, wprojT, D_EMB, D_EMB);
  transpose_bf16_kernel<<<dim3((DFF/32)*(D_EMB/32)),   dim3(256), 0, stream>>>(w_fc1,  wfc1T, D_EMB, DFF);
  transpose_bf16_kernel<<<dim3((D_EMB/32)*(DFF/32)),   dim3(256), 0, stream>>>(w_fc2,  wfc2T, DFF, D_EMB);
  zero_counter_kernel<<<dim3(1), dim3(1), 0, stream>>>(cnt);

  ln_kernel<<<dim3(S_LEN), dim3(256), 0, stream>>>(x, ln1_g, ln1_b, lnbuf);
  gemm_kernel<0><<<dim3((DQKV/128)*(S_LEN/128)), dim3(256), 0, stream>>>(
      lnbuf, wqkvT, b_qkv, nullptr, kqv, S_LEN, DQKV, D_EMB, D_EMB);
  attn_kernel<<<dim3(ATTN_BLOCKS), dim3(256), 0, stream>>>(kqv, ybuf, cnt);

  if (splitk) {
    gemm_kernel<3><<<dim3((D_EMB/128)*(S_LEN/128)*3), dim3(256), 0, stream>>>(
        ybuf, wprojT, nullptr, nullptr, part, S_LEN, D_EMB, D_EMB, D_EMB/3);
    reduce_kernel<3><<<dim3(1024), dim3(256), 0, stream>>>(part, b_proj, x, x1, MN4);
  } else {
    gemm_kernel<2><<<dim3((D_EMB/128)*(S_LEN/128)), dim3(256), 0, stream>>>(
        ybuf, wprojT, b_proj, x, x1, S_LEN, D_EMB, D_EMB, D_EMB);
  }

  ln_kernel<<<dim3(S_LEN), dim3(256), 0, stream>>>(x1, ln2_g, ln2_b, lnbuf);
  gemm_kernel<1><<<dim3((DFF/128)*(S_LEN/128)), dim3(256), 0, stream>>>(
      lnbuf, wfc1T, b_fc1, nullptr, hbuf, S_LEN, DFF, D_EMB, D_EMB);

  if (splitk) {
    gemm_kernel<3><<<dim3((D_EMB/128)*(S_LEN/128)*4), dim3(256), 0, stream>>>(
        hbuf, wfc2T, nullptr, nullptr, part, S_LEN, D_EMB, DFF, DFF/4);
    reduce_kernel<4><<<dim3(1024), dim3(256), 0, stream>>>(part, b_fc2, x1, (float*)d_out, MN4);
  } else {
    gemm_kernel<2><<<dim3((D_EMB/128)*(S_LEN/128)), dim3(256), 0, stream>>>(
        hbuf, wfc2T, b_fc2, x1, (float*)d_out, S_LEN, D_EMB, DFF, DFF);
  }
}

// Round 7
// 244.334 us; speedup vs baseline: 1.1320x; 1.0849x over previous
//
#include <hip/hip_runtime.h>
#include <hip/hip_bf16.h>

#define S_LEN 4096
#define D_EMB 768
#define NH    12
#define HD    64
#define DQKV  2304
#define DFF   3072

typedef __attribute__((ext_vector_type(4))) short short4v;
typedef __attribute__((ext_vector_type(8))) short short8v;
typedef __attribute__((ext_vector_type(4))) float float4v;

static __device__ __forceinline__ float4v mfma16(short4v a, short4v b, float4v c) {
  return __builtin_amdgcn_mfma_f32_16x16x16bf16_1k(a, b, c, 0, 0, 0);
}

static __device__ __forceinline__ short bf16bits(float f) {
  __hip_bfloat16 h = __float2bfloat16(f);
  return *reinterpret_cast<short*>(&h);
}

// async global -> LDS, 16B per lane. LDS dest must be wave-uniform base + lane*16.
static __device__ __forceinline__ void gload16(const __hip_bfloat16* g, __hip_bfloat16* l) {
  __builtin_amdgcn_global_load_lds((const __attribute__((address_space(1))) void*)g,
                                   (__attribute__((address_space(3))) void*)l, 16, 0, 0);
}

// ---------------- LayerNorm: fp32 in -> bf16 out, one block per row ----------------
__global__ __launch_bounds__(256) void ln_kernel(const float* __restrict__ x,
    const float* __restrict__ g, const float* __restrict__ b,
    __hip_bfloat16* __restrict__ out)
{
  int row = blockIdx.x;
  int tid = threadIdx.x;
  const float* xr = x + (size_t)row * D_EMB;
  float v0 = xr[tid], v1 = xr[tid + 256], v2 = xr[tid + 512];
  float s  = v0 + v1 + v2;
  float sq = v0 * v0 + v1 * v1 + v2 * v2;
  #pragma unroll
  for (int off = 32; off >= 1; off >>= 1) {
    s  += __shfl_xor(s, off);
    sq += __shfl_xor(sq, off);
  }
  __shared__ float ss[4], ssq[4];
  if ((tid & 63) == 0) { ss[tid >> 6] = s; ssq[tid >> 6] = sq; }
  __syncthreads();
  s  = ss[0] + ss[1] + ss[2] + ss[3];
  sq = ssq[0] + ssq[1] + ssq[2] + ssq[3];
  float mean = s * (1.0f / D_EMB);
  float var  = sq * (1.0f / D_EMB) - mean * mean;
  float rstd = rsqrtf(var + 1e-5f);
  __hip_bfloat16* orow = out + (size_t)row * D_EMB;
  orow[tid]       = __float2bfloat16((v0 - mean) * rstd * g[tid]       + b[tid]);
  orow[tid + 256] = __float2bfloat16((v1 - mean) * rstd * g[tid + 256] + b[tid + 256]);
  orow[tid + 512] = __float2bfloat16((v2 - mean) * rstd * g[tid + 512] + b[tid + 512]);
}

// ---------------- fp32 [K][N] -> bf16 [N][K] tiled transpose ----------------
__global__ __launch_bounds__(256) void transpose_bf16_kernel(const float* __restrict__ in,
    __hip_bfloat16* __restrict__ out, int K, int N)
{
  __shared__ float t[32][33];
  int nb = N >> 5;
  int bn = blockIdx.x % nb, bk = blockIdx.x / nb;
  int tx = threadIdx.x & 31, ty = threadIdx.x >> 5;
  #pragma unroll
  for (int i = 0; i < 4; i++)
    t[ty + 8 * i][tx] = in[(size_t)(bk * 32 + ty + 8 * i) * N + bn * 32 + tx];
  __syncthreads();
  #pragma unroll
  for (int i = 0; i < 4; i++)
    out[(size_t)(bn * 32 + ty + 8 * i) * K + bk * 32 + tx] = __float2bfloat16(t[tx][ty + 8 * i]);
}

// ---------------- GEMM (m97 structure): C = A[M,K] * Bt[N,K]^T ----------------
// EPI 0: +bias -> bf16   EPI 1: +bias, GELU -> bf16   EPI 2: +bias +resid -> fp32
// EPI 3: raw fp32 partial to Cout + split*M*N (no bias)
template<int EPI>
__global__ __launch_bounds__(256) void gemm_kernel(
    const __hip_bfloat16* __restrict__ A,
    const __hip_bfloat16* __restrict__ Bt,
    const float* __restrict__ bias,
    const float* __restrict__ resid,
    void* __restrict__ Cout,
    int M, int N, int Kfull, int kChunk)
{
  __shared__ __hip_bfloat16 Asm[128 * 64];
  __shared__ __hip_bfloat16 Bsm[128 * 64];
  int nb = N >> 7, mb = M >> 7;
  int tilesPer = nb * mb;
  int split = blockIdx.x / tilesPer;
  int b2 = blockIdx.x % tilesPer;
  int bx = b2 % nb, by = b2 / nb;
  int m0 = by << 7, n0 = bx << 7;
  int k0 = split * kChunk;
  int tid = threadIdx.x;
  int lane = tid & 63, lg = lane >> 4, li = lane & 15;
  int w = tid >> 6, wr = w >> 1, wc = w & 1;

  int sr  = tid >> 3;
  int scn = (tid & 7) ^ (sr & 7);
  const __hip_bfloat16* aSrc = A  + (size_t)(m0 + sr) * Kfull + k0 + scn * 8;
  const __hip_bfloat16* bSrc = Bt + (size_t)(n0 + sr) * Kfull + k0 + scn * 8;
  __hip_bfloat16* aDst = Asm + tid * 8;
  __hip_bfloat16* bDst = Bsm + tid * 8;
  const size_t rowStep = (size_t)32 * Kfull;

  float4v acc[4][4];
  #pragma unroll
  for (int i = 0; i < 4; i++)
    #pragma unroll
    for (int j = 0; j < 4; j++) {
      float4v z = {0.f, 0.f, 0.f, 0.f};
      acc[i][j] = z;
    }

  int sw = li & 7;

  for (int kt = 0; kt < kChunk; kt += 64) {
    #pragma unroll
    for (int i = 0; i < 4; i++) {
      gload16(aSrc + i * rowStep, aDst + i * 2048);
      gload16(bSrc + i * rowStep, bDst + i * 2048);
    }
    aSrc += 64; bSrc += 64;
    __syncthreads();
    #pragma unroll
    for (int kk = 0; kk < 2; kk++) {
      short8v af[4], bf[4];
      #pragma unroll
      for (int f = 0; f < 4; f++) {
        int ar = wr * 64 + f * 16 + li;
        int br = wc * 64 + f * 16 + li;
        int ch = ((kk << 2) | lg) ^ sw;
        af[f] = *(const short8v*)(Asm + ar * 64 + ch * 8);
        bf[f] = *(const short8v*)(Bsm + br * 64 + ch * 8);
      }
      #pragma unroll
      for (int fr = 0; fr < 4; fr++)
        #pragma unroll
        for (int fc = 0; fc < 4; fc++)
          acc[fr][fc] = __builtin_amdgcn_mfma_f32_16x16x32_bf16(af[fr], bf[fc], acc[fr][fc], 0, 0, 0);
    }
    __syncthreads();
  }

  #pragma unroll
  for (int fr = 0; fr < 4; fr++) {
    int row = m0 + wr * 64 + fr * 16 + lg * 4;
    #pragma unroll
    for (int fc = 0; fc < 4; fc++) {
      int col = n0 + wc * 64 + fc * 16 + li;
      float bv = (EPI == 3) ? 0.f : bias[col];
      #pragma unroll
      for (int r = 0; r < 4; r++) {
        float v = acc[fr][fc][r] + bv;
        size_t idx = (size_t)(row + r) * N + col;
        if (EPI == 1) {
          v = 0.5f * v * (1.0f + erff(v * 0.70710678118654752f));
          ((__hip_bfloat16*)Cout)[idx] = __float2bfloat16(v);
        } else if (EPI == 2) {
          ((float*)Cout)[idx] = v + resid[idx];
        } else if (EPI == 3) {
          ((float*)Cout)[(size_t)split * M * N + idx] = v;
        } else {
          ((__hip_bfloat16*)Cout)[idx] = __float2bfloat16(v);
        }
      }
    }
  }
}

// ---------------- split-K reduce: out = resid + bias + sum(parts) ----------------
template<int NS>
__global__ __launch_bounds__(256) void reduce_kernel(const float* __restrict__ parts,
    const float* __restrict__ bias, const float* __restrict__ resid,
    float* __restrict__ out, int n4)
{
  int stride = gridDim.x * 256;
  for (int e = blockIdx.x * 256 + threadIdx.x; e < n4; e += stride) {
    float4v acc = *(const float4v*)(resid + 4 * (size_t)e);
    int col = (e * 4) % D_EMB;
    float4v bv = *(const float4v*)(bias + col);
    acc += bv;
    #pragma unroll
    for (int s = 0; s < NS; s++)
      acc += *(const float4v*)(parts + (size_t)s * 4 * n4 + 4 * (size_t)e);
    *(float4v*)(out + 4 * (size_t)e) = acc;
  }
}

// ---------------- causal flash attention v7: kv-split flash-decoding ----------------
// SPLIT=true: 1920 blocks; chunk of <=16 kv tiles. Tasks with qb<16 write y directly;
// others write fp32 partials (O^T[d][q], m, l in exp2 domain) for the combine kernel.
// SPLIT=false fallback: 768 blocks, full kv range, direct write.
// Partial slot layout: 4224 floats = O[64 d][64 q] + m[64] + l[64].
template<bool SPLIT>
__global__ __launch_bounds__(256) void attn_kernel(const __hip_bfloat16* __restrict__ kqv,
                                                   __hip_bfloat16* __restrict__ y,
                                                   float* __restrict__ partial)
{
  __shared__ __hip_bfloat16 Ksm[64 * 64];   // [kv][d] linear, swizzled content
  __shared__ __hip_bfloat16 Vtsm[64][68];   // [d][kv], pad -> conflict-free b64 reads

  int bid = blockIdx.x;
  int h, qb, c;
  if (SPLIT) {
    h = bid / 160;
    int t = bid % 160;                      // heavy (big qb) first in each segment
    if      (t < 64)  { c = 0; qb = 63 - t; }
    else if (t < 112) { c = 1; qb = 63 - (t - 64); }
    else if (t < 144) { c = 2; qb = 63 - (t - 112); }
    else              { c = 3; qb = 63 - (t - 144); }
  } else {
    h = bid / 64; qb = 63 - (bid % 64); c = 0;
  }
  int nch   = SPLIT ? (qb >> 4) + 1 : 1;
  int kt0   = c << 4;
  int kt1   = SPLIT ? min(kt0 + 16, qb + 1) : qb + 1;
  bool direct = (nch == 1);

  int tid = threadIdx.x;
  int w = tid >> 6, lane = tid & 63, lg = lane >> 4, li = lane & 15;
  int sw = li & 7;

  // staging roles
  int ksr  = tid >> 3;
  int kscn = (tid & 7) ^ (ksr & 7);
  int vr = (tid >> 3) << 1, vc = (tid & 7) << 3;
  const __hip_bfloat16* kSrc0 = kqv + h * HD + (size_t)ksr * DQKV + kscn * 8;
  const __hip_bfloat16* vSrc0 = kqv + 2 * D_EMB + h * HD + (size_t)vr * DQKV + vc;
  const size_t kRowStep = (size_t)32 * DQKV;
  const float scl = 0.18033688011f;         // 0.125 * log2(e)

  // Q as B-operand of 16x16x32: lane li = q-col, k(d) = kk*32 + 8*lg + j
  short8v q8[2];
  {
    const __hip_bfloat16* qp = kqv + (size_t)(qb * 64 + w * 16 + li) * DQKV + D_EMB + h * HD + 8 * lg;
    q8[0] = *(const short8v*)(qp);
    q8[1] = *(const short8v*)(qp + 32);
  }

  float m = -1e30f, lsum = 0.f;
  float4v o[4];
  #pragma unroll
  for (int fc = 0; fc < 4; fc++) { float4v z = {0.f,0.f,0.f,0.f}; o[fc] = z; }

  short8v vA, vB;
  vA = *(const short8v*)(vSrc0 + (size_t)kt0 * 64 * DQKV);
  vB = *(const short8v*)(vSrc0 + (size_t)kt0 * 64 * DQKV + DQKV);

  for (int kb = kt0; kb < kt1; kb++) {
    __syncthreads();                        // prev-tile LDS reads done; V regs landed
    {
      const __hip_bfloat16* ks = kSrc0 + (size_t)kb * 64 * DQKV;
      gload16(ks,            Ksm + tid * 8);
      gload16(ks + kRowStep, Ksm + tid * 8 + 2048);
    }
    #pragma unroll
    for (int j = 0; j < 8; j++) {
      unsigned int pk = (unsigned int)(unsigned short)vA[j]
                      | ((unsigned int)(unsigned short)vB[j] << 16);
      *reinterpret_cast<unsigned int*>(&Vtsm[vc + j][vr]) = pk;
    }
    __syncthreads();                        // drains vmcnt: K staged, V written

    if (kb + 1 < kt1) {                     // V reg prefetch
      const __hip_bfloat16* vs = vSrc0 + (size_t)(kb + 1) * 64 * DQKV;
      vA = *(const short8v*)(vs);
      vB = *(const short8v*)(vs + DQKV);
    }

    // S^T = K * Q^T : s[fc] covers kv = fc*16 + 4*lg + r, q = li
    float4v s[4];
    #pragma unroll
    for (int fc = 0; fc < 4; fc++) { float4v z = {0.f,0.f,0.f,0.f}; s[fc] = z; }
    #pragma unroll
    for (int kk = 0; kk < 2; kk++) {
      #pragma unroll
      for (int fc = 0; fc < 4; fc++) {
        int ch = ((kk << 2) | lg) ^ sw;
        short8v kf = *(const short8v*)(Ksm + (fc * 16 + li) * 64 + ch * 8);
        s[fc] = __builtin_amdgcn_mfma_f32_16x16x32_bf16(kf, q8[kk], s[fc], 0, 0, 0);
      }
    }

    // online softmax (exp2 domain, defer-max THR=8)
    bool diag = (kb == qb);
    float pmax = -1e30f;
    #pragma unroll
    for (int fc = 0; fc < 4; fc++) {
      #pragma unroll
      for (int rr = 0; rr < 4; rr++) {
        float v = s[fc][rr] * scl;
        if (diag && (fc * 16 + 4 * lg + rr) > (w * 16 + li)) v = -1e30f;
        s[fc][rr] = v;
        pmax = fmaxf(pmax, v);
      }
    }
    pmax = fmaxf(pmax, __shfl_xor(pmax, 16));
    pmax = fmaxf(pmax, __shfl_xor(pmax, 32));
    if (!__all(pmax - m <= 8.0f)) {
      float mn = fmaxf(m, pmax);
      float alpha = exp2f(m - mn);
      lsum *= alpha;
      #pragma unroll
      for (int fc = 0; fc < 4; fc++) {
        #pragma unroll
        for (int rr = 0; rr < 4; rr++) o[fc][rr] *= alpha;
      }
      m = mn;
    }
    float rs = 0.f;
    #pragma unroll
    for (int fc = 0; fc < 4; fc++) {
      #pragma unroll
      for (int rr = 0; rr < 4; rr++) {
        float pv = exp2f(s[fc][rr] - m);
        s[fc][rr] = pv;
        rs += pv;
      }
    }
    rs += __shfl_xor(rs, 16);
    rs += __shfl_xor(rs, 32);
    lsum += rs;

    // P^T fragments (B-operand of 16x16x16) straight from registers
    short4v pb[4];
    #pragma unroll
    for (int kk = 0; kk < 4; kk++) {
      short4v t;
      #pragma unroll
      for (int rr = 0; rr < 4; rr++) t[rr] = bf16bits(s[kk][rr]);
      pb[kk] = t;
    }

    // O^T += V^T * P^T
    #pragma unroll
    for (int kk = 0; kk < 4; kk++) {
      #pragma unroll
      for (int fc = 0; fc < 4; fc++) {
        short4v vf = *(const short4v*)(&Vtsm[fc * 16 + li][kk * 16 + 4 * lg]);
        o[fc] = mfma16(vf, pb[kk], o[fc]);
      }
    }
  }

  if (direct) {
    float inv = 1.0f / lsum;
    int qrow = qb * 64 + w * 16 + li;
    #pragma unroll
    for (int fc = 0; fc < 4; fc++) {
      short4v ov;
      #pragma unroll
      for (int rr = 0; rr < 4; rr++) ov[rr] = bf16bits(o[fc][rr] * inv);
      *reinterpret_cast<short4v*>(y + (size_t)qrow * D_EMB + h * HD + fc * 16 + 4 * lg) = ov;
    }
  } else {
    int offq = (qb < 32) ? (qb - 16) * 2 : (qb < 48) ? 32 + (qb - 32) * 3 : 80 + (qb - 48) * 4;
    float* ps = partial + (size_t)(h * 144 + offq + c) * 4224;
    int q = w * 16 + li;
    #pragma unroll
    for (int fc = 0; fc < 4; fc++) {
      #pragma unroll
      for (int rr = 0; rr < 4; rr++)
        ps[(fc * 16 + 4 * lg + rr) * 64 + q] = o[fc][rr];
    }
    if (lg == 0) {
      ps[4096 + q] = m;
      ps[4160 + q] = lsum;
    }
  }
}

// ---------------- attn combine: merge <=4 kv-chunks per (h, qb>=16) task ----------------
__global__ __launch_bounds__(256) void attn_combine_kernel(const float* __restrict__ partial,
                                                           __hip_bfloat16* __restrict__ y)
{
  int task = blockIdx.x;            // 576 = 12 * 48
  int h  = task / 48;
  int qb = 16 + task % 48;
  int nch = (qb >> 4) + 1;
  int offq = (qb < 32) ? (qb - 16) * 2 : (qb < 48) ? 32 + (qb - 32) * 3 : 80 + (qb - 48) * 4;
  const float* base = partial + (size_t)(h * 144 + offq) * 4224;
  int wv = threadIdx.x >> 6;        // d-group (16 d rows)
  int lane = threadIdx.x & 63;      // q

  float mv[4], lv[4];
  float M = -1e30f;
  #pragma unroll
  for (int c = 0; c < 4; c++) {
    if (c < nch) {
      mv[c] = base[c * 4224 + 4096 + lane];
      lv[c] = base[c * 4224 + 4160 + lane];
      M = fmaxf(M, mv[c]);
    } else { mv[c] = -1e30f; lv[c] = 0.f; }
  }
  float L = 0.f;
  float acc[16];
  #pragma unroll
  for (int j = 0; j < 16; j++) acc[j] = 0.f;
  #pragma unroll
  for (int c = 0; c < 4; c++) {
    if (c < nch) {
      float wgt = exp2f(mv[c] - M);
      L += wgt * lv[c];
      const float* O = base + c * 4224;
      #pragma unroll
      for (int j = 0; j < 16; j++)
        acc[j] += wgt * O[(wv * 16 + j) * 64 + lane];
    }
  }
  float inv = 1.0f / L;
  __hip_bfloat16* yp = y + (size_t)(qb * 64 + lane) * D_EMB + h * HD + wv * 16;
  short8v o0, o1;
  #pragma unroll
  for (int j = 0; j < 8; j++) o0[j] = bf16bits(acc[j] * inv);
  #pragma unroll
  for (int j = 0; j < 8; j++) o1[j] = bf16bits(acc[8 + j] * inv);
  *reinterpret_cast<short8v*>(yp)     = o0;
  *reinterpret_cast<short8v*>(yp + 8) = o1;
}

// ---------------- launch ----------------
extern "C" void kernel_launch(void* const* d_in, const int* in_sizes, int n_in,
                              void* d_out, int out_size, void* d_ws, size_t ws_size,
                              hipStream_t stream)
{
  const float* x      = (const float*)d_in[0];
  const float* w_qkv  = (const float*)d_in[1];
  const float* b_qkv  = (const float*)d_in[2];
  const float* w_proj = (const float*)d_in[3];
  const float* b_proj = (const float*)d_in[4];
  const float* w_fc1  = (const float*)d_in[5];
  const float* b_fc1  = (const float*)d_in[6];
  const float* w_fc2  = (const float*)d_in[7];
  const float* b_fc2  = (const float*)d_in[8];
  const float* ln1_g  = (const float*)d_in[9];
  const float* ln1_b  = (const float*)d_in[10];
  const float* ln2_g  = (const float*)d_in[11];
  const float* ln2_b  = (const float*)d_in[12];

  char* ws = (char*)d_ws;
  size_t off = 0;
  __hip_bfloat16* wqkvT = (__hip_bfloat16*)(ws + off); off += (size_t)DQKV * D_EMB * 2;
  __hip_bfloat16* wprojT= (__hip_bfloat16*)(ws + off); off += (size_t)D_EMB * D_EMB * 2;
  __hip_bfloat16* wfc1T = (__hip_bfloat16*)(ws + off); off += (size_t)DFF * D_EMB * 2;
  __hip_bfloat16* wfc2T = (__hip_bfloat16*)(ws + off); off += (size_t)D_EMB * DFF * 2;
  __hip_bfloat16* lnbuf = (__hip_bfloat16*)(ws + off); off += (size_t)S_LEN * D_EMB * 2;
  __hip_bfloat16* kqv   = (__hip_bfloat16*)(ws + off);
  __hip_bfloat16* hbuf  = kqv;                         off += (size_t)S_LEN * DQKV * 2;
  __hip_bfloat16* ybuf  = (__hip_bfloat16*)(ws + off); off += (size_t)S_LEN * D_EMB * 2;
  float*          x1    = (float*)(ws + off);          off += (size_t)S_LEN * D_EMB * 4;
  float*          part  = (float*)(ws + off);          // split-K planes; attn partials alias
  size_t needSplit = off + (size_t)4 * S_LEN * D_EMB * 4;
  size_t needAttn  = off + (size_t)1728 * 4224 * 4;    // 29.2 MB < split-K planes
  bool splitk  = (ws_size >= needSplit);
  bool attnSpl = (ws_size >= needAttn);
  const int MN4 = S_LEN * D_EMB / 4;
  (void)in_sizes; (void)n_in; (void)out_size;

  transpose_bf16_kernel<<<dim3((DQKV/32)*(D_EMB/32)), dim3(256), 0, stream>>>(w_qkv,  wqkvT, D_EMB, DQKV);
  transpose_bf16_kernel<<<dim3((D_EMB/32)*(D_EMB/32)), dim3(256), 0, stream>>>(w_proj, wprojT, D_EMB, D_EMB);
  transpose_bf16_kernel<<<dim3((DFF/32)*(D_EMB/32)),   dim3(256), 0, stream>>>(w_fc1,  wfc1T, D_EMB, DFF);
  transpose_bf16_kernel<<<dim3((D_EMB/32)*(DFF/32)),   dim3(256), 0, stream>>>(w_fc2,  wfc2T, DFF, D_EMB);

  ln_kernel<<<dim3(S_LEN), dim3(256), 0, stream>>>(x, ln1_g, ln1_b, lnbuf);
  gemm_kernel<0><<<dim3((DQKV/128)*(S_LEN/128)), dim3(256), 0, stream>>>(
      lnbuf, wqkvT, b_qkv, nullptr, kqv, S_LEN, DQKV, D_EMB, D_EMB);

  if (attnSpl) {
    attn_kernel<true><<<dim3(1920), dim3(256), 0, stream>>>(kqv, ybuf, part);
    attn_combine_kernel<<<dim3(576), dim3(256), 0, stream>>>(part, ybuf);
  } else {
    attn_kernel<false><<<dim3(768), dim3(256), 0, stream>>>(kqv, ybuf, part);
  }

  if (splitk) {
    gemm_kernel<3><<<dim3((D_EMB/128)*(S_LEN/128)*3), dim3(256), 0, stream>>>(
        ybuf, wprojT, nullptr, nullptr, part, S_LEN, D_EMB, D_EMB, D_EMB/3);
    reduce_kernel<3><<<dim3(1024), dim3(256), 0, stream>>>(part, b_proj, x, x1, MN4);
  } else {
    gemm_kernel<2><<<dim3((D_EMB/128)*(S_LEN/128)), dim3(256), 0, stream>>>(
        ybuf, wprojT, b_proj, x, x1, S_LEN, D_EMB, D_EMB, D_EMB);
  }

  ln_kernel<<<dim3(S_LEN), dim3(256), 0, stream>>>(x1, ln2_g, ln2_b, lnbuf);
  gemm_kernel<1><<<dim3((DFF/128)*(S_LEN/128)), dim3(256), 0, stream>>>(
      lnbuf, wfc1T, b_fc1, nullptr, hbuf, S_LEN, DFF, D_EMB, D_EMB);

  if (splitk) {
    gemm_kernel<3><<<dim3((D_EMB/128)*(S_LEN/128)*4), dim3(256), 0, stream>>>(
        hbuf, wfc2T, nullptr, nullptr, part, S_LEN, D_EMB, DFF, DFF/4);
    reduce_kernel<4><<<dim3(1024), dim3(256), 0, stream>>>(part, b_fc2, x1, (float*)d_out, MN4);
  } else {
    gemm_kernel<2><<<dim3((D_EMB/128)*(S_LEN/128)), dim3(256), 0, stream>>>(
        hbuf, wfc2T, b_fc2, x1, (float*)d_out, S_LEN, D_EMB, DFF, DFF);
  }
}